// Round 7
// baseline (50.905 us; speedup 1.0000x reference)
//
#include <hip/hip_runtime.h>

// MODWT (sym4, level 5, no à-trous upsampling) — outputs h4, h5, lowpass5 as (B,1,3,T).
//
// Circular cross-correlations compose: each output is ONE circular FIR of x.
//   h4[t]  = sum_m F4[m] x[(t+m-16) mod T],  F4 = lo*lo*lo*hi  (29 taps)
//   h5[t]  = sum_m F5[m] x[(t+m-20) mod T],  F5 = lo^4 * hi    (36 taps)
//   lo5[t] = sum_m FL[m] x[(t+m-20) mod T],  FL = lo^5         (36 taps)
//
// Round 7: R6 structure (4 outputs/thread, no LDS, no barriers, plain stores)
// + packed fp32 FMA: the two 36-tap planes (h5, lo5) accumulate in a float2
// via v_pk_fma_f32 (VOP3P, 2 f32 FMA per instruction, IEEE fp32 — no precision
// change). Broadcast w[m+j] feeds both halves via op_sel. FMA instructions
// per thread: 404 -> 260 (-36% VALU issue). Single-variable change vs R6.

typedef float f4v __attribute__((ext_vector_type(4)));
typedef float f2v __attribute__((ext_vector_type(2)));

static constexpr float SYM4_LO[8] = {
    -0.07576571478927333f, -0.02963552764599851f, 0.49761866763201545f,
     0.8037387518059161f,   0.29785779560527736f, -0.09921954357684722f,
    -0.012603967262037833f, 0.032223100604071304f};
static constexpr float SYM4_HI[8] = {
    -0.032223100604071304f, -0.012603967262037833f, 0.09921954357684722f,
     0.29785779560527736f,  -0.8037387518059161f,   0.49761866763201545f,
     0.02963552764599851f,  -0.07576571478927333f};

struct FiltPack {
    float f4[36];  // h4 filter padded to window [t-20, t+15] (zeros m<4, m>32)
    float f5[36];
    float fl[36];
};

constexpr FiltPack make_filters() {
    double lo[8], hi[8];
    for (int i = 0; i < 8; ++i) { lo[i] = SYM4_LO[i]; hi[i] = SYM4_HI[i]; }
    double l2[15] = {}, l3[22] = {}, l4[29] = {};
    for (int i = 0; i < 8;  ++i) for (int j = 0; j < 8; ++j) l2[i + j] += lo[i] * lo[j];
    for (int i = 0; i < 15; ++i) for (int j = 0; j < 8; ++j) l3[i + j] += l2[i] * lo[j];
    for (int i = 0; i < 22; ++i) for (int j = 0; j < 8; ++j) l4[i + j] += l3[i] * lo[j];
    double f4[29] = {}, f5[36] = {}, fl[36] = {};
    for (int i = 0; i < 22; ++i) for (int j = 0; j < 8; ++j) f4[i + j] += l3[i] * hi[j];
    for (int i = 0; i < 29; ++i) for (int j = 0; j < 8; ++j) f5[i + j] += l4[i] * hi[j];
    for (int i = 0; i < 29; ++i) for (int j = 0; j < 8; ++j) fl[i + j] += l4[i] * lo[j];
    FiltPack r = {};
    for (int m = 0; m < 36; ++m) {
        r.f4[m] = (m >= 4 && m < 33) ? (float)f4[m - 4] : 0.0f;
        r.f5[m] = (float)f5[m];
        r.fl[m] = (float)fl[m];
    }
    return r;
}
static constexpr FiltPack FP = make_filters();

__global__ __launch_bounds__(256)
void modwt_direct_kernel(const float* __restrict__ x, float* __restrict__ out, int Tn) {
    const int T4 = Tn >> 2;                               // float4 chunks per row
    const int g  = blockIdx.x * 256 + threadIdx.x;        // global output-quad id
    const int b  = g / T4;                                // batch row
    const int c  = g - b * T4;                            // chunk within row
    // Outputs t0..t0+3, t0 = 4c. Window floats [t0-20, t0+19] = chunks c-5..c+4.

    const f4v* xr = reinterpret_cast<const f4v*>(x) + (size_t)b * T4;

    float w[40];
    if (c >= 5 && c + 5 <= T4) {
        // Fast path: one base pointer, 10 loads with immediate offsets.
        const f4v* p = xr + (c - 5);
        #pragma unroll
        for (int j = 0; j < 10; ++j)
            reinterpret_cast<f4v*>(w)[j] = p[j];
    } else {
        #pragma unroll
        for (int j = 0; j < 10; ++j) {
            int gc = c - 5 + j;
            if (gc < 0)    gc += T4;
            if (gc >= T4)  gc -= T4;
            reinterpret_cast<f4v*>(w)[j] = xr[gc];
        }
    }

    // a54[j] = (h5_acc, lo5_acc) packed -> v_pk_fma_f32; h4 scalar.
    f2v  a54[4] = {{0.f, 0.f}, {0.f, 0.f}, {0.f, 0.f}, {0.f, 0.f}};
    float a4[4] = {0.f, 0.f, 0.f, 0.f};
    #pragma unroll
    for (int m = 0; m < 36; ++m) {
        const f2v  c54 = {FP.f5[m], FP.fl[m]};  // constexpr -> hoisted constants
        const float c4v = FP.f4[m];             // zero taps skipped at compile time
        #pragma unroll
        for (int j = 0; j < 4; ++j) {
            const float xv = w[m + j];
            const f2v  xv2 = {xv, xv};          // op_sel broadcast, no extra mov
            a54[j] = __builtin_elementwise_fma(xv2, c54, a54[j]);
            if (c4v != 0.0f) a4[j] = fmaf(c4v, xv, a4[j]);
        }
    }

    // out (B,1,3,T): plane s at (b*3+s)*T. Plain stores (best in R6 A/B).
    f4v* o4 = reinterpret_cast<f4v*>(out);
    const size_t base = ((size_t)b * 3) * T4 + c;
    o4[base]                  = (f4v){a4[0],    a4[1],    a4[2],    a4[3]};
    o4[base + T4]             = (f4v){a54[0].x, a54[1].x, a54[2].x, a54[3].x};
    o4[base + 2 * (size_t)T4] = (f4v){a54[0].y, a54[1].y, a54[2].y, a54[3].y};
}

extern "C" void kernel_launch(void* const* d_in, const int* in_sizes, int n_in,
                              void* d_out, int out_size, void* d_ws, size_t ws_size,
                              hipStream_t stream) {
    const float* x = (const float*)d_in[0];
    float* out = (float*)d_out;
    const int B  = 16;
    const int Tn = in_sizes[0] / B;            // 1048576
    const int totalQuads = B * (Tn / 4);       // 4,194,304 output-quads

    dim3 grid(totalQuads / 256);               // 16384 blocks
    dim3 block(256);
    modwt_direct_kernel<<<grid, block, 0, stream>>>(x, out, Tn);
}

// Round 8
// 50.374 us; speedup vs baseline: 1.0106x; 1.0106x over previous
//
#include <hip/hip_runtime.h>

// MODWT (sym4, level 5, no à-trous upsampling) — outputs h4, h5, lowpass5 as (B,1,3,T).
//
// Circular cross-correlations compose: each output is ONE circular FIR of x.
//   h4[t]  = sum_m F4[m] x[(t+m-16) mod T],  F4 = lo*lo*lo*hi  (29 taps)
//   h5[t]  = sum_m F5[m] x[(t+m-20) mod T],  F5 = lo^4 * hi    (36 taps)
//   lo5[t] = sum_m FL[m] x[(t+m-20) mod T],  FL = lo^5         (36 taps)
//
// Round 8: R6 structure (4 outputs/thread, no LDS, no barriers, plain stores,
// best at 50.5 µs) + T1 XCD-aware block swizzle. Default round-robin dispatch
// scatters consecutive blocks across the 8 XCDs, so each XCD's L2 sees ~128
// interleaved 1-6 KB streams (1 read + 3 writes per block x 32 scattered CUs)
// -> HBM row thrash. Bijective swizzle swz=(bid&7)*(nwg/8)+(bid>>3) gives each
// XCD a contiguous 1/8 of the grid: 4 long sequential streams per XCD.
// Single-variable change vs R6.

typedef float f4v __attribute__((ext_vector_type(4)));

static constexpr float SYM4_LO[8] = {
    -0.07576571478927333f, -0.02963552764599851f, 0.49761866763201545f,
     0.8037387518059161f,   0.29785779560527736f, -0.09921954357684722f,
    -0.012603967262037833f, 0.032223100604071304f};
static constexpr float SYM4_HI[8] = {
    -0.032223100604071304f, -0.012603967262037833f, 0.09921954357684722f,
     0.29785779560527736f,  -0.8037387518059161f,   0.49761866763201545f,
     0.02963552764599851f,  -0.07576571478927333f};

struct FiltPack {
    float f4[36];  // h4 filter padded to window [t-20, t+15] (zeros m<4, m>32)
    float f5[36];
    float fl[36];
};

constexpr FiltPack make_filters() {
    double lo[8], hi[8];
    for (int i = 0; i < 8; ++i) { lo[i] = SYM4_LO[i]; hi[i] = SYM4_HI[i]; }
    double l2[15] = {}, l3[22] = {}, l4[29] = {};
    for (int i = 0; i < 8;  ++i) for (int j = 0; j < 8; ++j) l2[i + j] += lo[i] * lo[j];
    for (int i = 0; i < 15; ++i) for (int j = 0; j < 8; ++j) l3[i + j] += l2[i] * lo[j];
    for (int i = 0; i < 22; ++i) for (int j = 0; j < 8; ++j) l4[i + j] += l3[i] * lo[j];
    double f4[29] = {}, f5[36] = {}, fl[36] = {};
    for (int i = 0; i < 22; ++i) for (int j = 0; j < 8; ++j) f4[i + j] += l3[i] * hi[j];
    for (int i = 0; i < 29; ++i) for (int j = 0; j < 8; ++j) f5[i + j] += l4[i] * hi[j];
    for (int i = 0; i < 29; ++i) for (int j = 0; j < 8; ++j) fl[i + j] += l4[i] * lo[j];
    FiltPack r = {};
    for (int m = 0; m < 36; ++m) {
        r.f4[m] = (m >= 4 && m < 33) ? (float)f4[m - 4] : 0.0f;
        r.f5[m] = (float)f5[m];
        r.fl[m] = (float)fl[m];
    }
    return r;
}
static constexpr FiltPack FP = make_filters();

__global__ __launch_bounds__(256)
void modwt_direct_kernel(const float* __restrict__ x, float* __restrict__ out, int Tn) {
    const int T4 = Tn >> 2;                               // float4 chunks per row
    // T1 XCD swizzle: round-robin dispatch sends block i to XCD i%8; remap so
    // each XCD processes a contiguous 1/8 of the grid (long sequential streams).
    const int nwg8 = gridDim.x >> 3;                      // 2048
    const int bid  = blockIdx.x;
    const int swz  = (bid & 7) * nwg8 + (bid >> 3);       // bijective (nwg%8==0)
    const int g  = swz * 256 + threadIdx.x;               // global output-quad id
    const int b  = g / T4;                                // batch row
    const int c  = g - b * T4;                            // chunk within row
    // Outputs t0..t0+3, t0 = 4c. Window floats [t0-20, t0+19] = chunks c-5..c+4.

    const f4v* xr = reinterpret_cast<const f4v*>(x) + (size_t)b * T4;

    float w[40];
    if (c >= 5 && c + 5 <= T4) {
        // Fast path: one base pointer, 10 loads with immediate offsets.
        const f4v* p = xr + (c - 5);
        #pragma unroll
        for (int j = 0; j < 10; ++j)
            reinterpret_cast<f4v*>(w)[j] = p[j];
    } else {
        #pragma unroll
        for (int j = 0; j < 10; ++j) {
            int gc = c - 5 + j;
            if (gc < 0)    gc += T4;
            if (gc >= T4)  gc -= T4;
            reinterpret_cast<f4v*>(w)[j] = xr[gc];
        }
    }

    float a4[4] = {0.f, 0.f, 0.f, 0.f};
    float a5[4] = {0.f, 0.f, 0.f, 0.f};
    float al[4] = {0.f, 0.f, 0.f, 0.f};
    #pragma unroll
    for (int m = 0; m < 36; ++m) {
        const float c4v = FP.f4[m];   // constexpr -> folded; zero taps skipped
        const float c5v = FP.f5[m];
        const float clv = FP.fl[m];
        #pragma unroll
        for (int j = 0; j < 4; ++j) {
            const float xv = w[m + j];
            if (c4v != 0.0f) a4[j] = fmaf(c4v, xv, a4[j]);
            a5[j] = fmaf(c5v, xv, a5[j]);
            al[j] = fmaf(clv, xv, al[j]);
        }
    }

    // out (B,1,3,T): plane s at (b*3+s)*T. Plain stores (best in R6 A/B).
    f4v* o4 = reinterpret_cast<f4v*>(out);
    const size_t base = ((size_t)b * 3) * T4 + c;
    o4[base]                  = (f4v){a4[0], a4[1], a4[2], a4[3]};
    o4[base + T4]             = (f4v){a5[0], a5[1], a5[2], a5[3]};
    o4[base + 2 * (size_t)T4] = (f4v){al[0], al[1], al[2], al[3]};
}

extern "C" void kernel_launch(void* const* d_in, const int* in_sizes, int n_in,
                              void* d_out, int out_size, void* d_ws, size_t ws_size,
                              hipStream_t stream) {
    const float* x = (const float*)d_in[0];
    float* out = (float*)d_out;
    const int B  = 16;
    const int Tn = in_sizes[0] / B;            // 1048576
    const int totalQuads = B * (Tn / 4);       // 4,194,304 output-quads

    dim3 grid(totalQuads / 256);               // 16384 blocks (divisible by 8)
    dim3 block(256);
    modwt_direct_kernel<<<grid, block, 0, stream>>>(x, out, Tn);
}